// Round 3
// baseline (448.290 us; speedup 1.0000x reference)
//
#include <hip/hip_runtime.h>
#include <hip/hip_bf16.h>

// Problem constants (fixed by reference): N=262144 rows, D=64, K=512 codes.
#define N_ROWS 262144
#define DIM 64
#define KC 512

// d_out layout — FLOAT32 (confirmed R2: outputs 0/1 passed with this layout):
//   out[0]                      = loss
//   out[1 .. 1+N*D)             = quantized [N,64] row-major
//   out[1+N*D .. 1+N*D+N)       = float(encoding_indices)
//
// Indices must match np.argmin of the reference's FLOAT32 distance array
// bit-for-bit (threshold 10.24 on bf16-viewed indices => essentially exact).
// We replicate numpy's f32 numerics:
//   x_sq, e_sq : numpy pairwise sum, n=64 => 8-accumulator striped scheme,
//                squares rounded separately (no FMA)
//   dot        : OpenBLAS sgemm microkernel = sequential fused-FMA chain
//   d          : fl( fl(x_sq + e_sq_k) - 2*dot_k ), contraction off
//   argmin     : strict <, first-min-wins

// numpy pairwise sum of squares for n=64 (scalar path, PW_BLOCKSIZE=128):
//   r[j] = sum_{i ≡ j mod 8} fl(a_i*a_i), sequential in i;
//   res  = ((r0+r1)+(r2+r3)) + ((r4+r5)+(r6+r7))
__device__ __forceinline__ float np_sumsq64(const float* a) {
#pragma clang fp contract(off)
    float r[8];
#pragma unroll
    for (int j = 0; j < 8; ++j) r[j] = a[j] * a[j];
#pragma unroll
    for (int i = 8; i < 64; i += 8)
#pragma unroll
        for (int j = 0; j < 8; ++j) r[j] = r[j] + a[i + j] * a[i + j];
    return ((r[0] + r[1]) + (r[2] + r[3])) + ((r[4] + r[5]) + (r[6] + r[7]));
}

// ---- kernel 1: e_sq_k with numpy bit-exact summation ----
__global__ void esq_kernel(const float* __restrict__ cb, float* __restrict__ esq) {
    int k = blockIdx.x * blockDim.x + threadIdx.x;
    if (k < KC) esq[k] = np_sumsq64(cb + k * DIM);
}

// ---- kernel 2: main VQ — one thread per row ----
__global__ __launch_bounds__(256) void vq_kernel(
    const float* __restrict__ x, const float* __restrict__ cb,
    const float* __restrict__ esq, float* __restrict__ out,
    float* __restrict__ loss_acc)
{
    const int row = blockIdx.x * 256 + threadIdx.x;
    if (row >= N_ROWS) return;

    // Row into 64 VGPRs (16x float4, 256B-aligned).
    float xr[DIM];
    const float4* xv = reinterpret_cast<const float4*>(x + (size_t)row * DIM);
#pragma unroll
    for (int j = 0; j < DIM / 4; ++j) {
        float4 v = xv[j];
        xr[4 * j + 0] = v.x; xr[4 * j + 1] = v.y;
        xr[4 * j + 2] = v.z; xr[4 * j + 3] = v.w;
    }

    // numpy-exact ||x||^2 (f32 bits matter: they set where fl(x_sq+e_sq)
    // lands relative to rounding boundaries).
    const float xsq = np_sumsq64(xr);

    // Replicated reference distance, argmin first-min-wins.
    float best = 3.4e38f;
    int bidx = 0;
    for (int k = 0; k < KC; ++k) {
        const float* e = cb + k * DIM;   // wave-uniform -> s_load
        // sgemm-style dot: single accumulator, sequential fused FMA.
        float dot = 0.f;
#pragma unroll
        for (int j = 0; j < DIM; ++j) dot = fmaf(xr[j], e[j], dot);
        float d;
        {
#pragma clang fp contract(off)
            float t1 = xsq + esq[k];     // rounds (ufunc pass 1)
            d = t1 - 2.0f * dot;         // 2*dot exact; subtract rounds (pass 2)
        }
        if (d < best) { best = d; bidx = k; }
    }

    // quantized = codebook[bidx]
    const float* eb = cb + (size_t)bidx * DIM;
    float* q = out + 1 + (size_t)row * DIM;
#pragma unroll
    for (int j = 0; j < DIM; ++j) q[j] = eb[j];

    out[1 + (size_t)N_ROWS * DIM + row] = (float)bidx;

    // loss contribution: ||x - e||^2 = d_best (noise ~1e-5, threshold ~2%)
    float lrow = best;
#pragma unroll
    for (int off = 32; off > 0; off >>= 1) lrow += __shfl_down(lrow, off, 64);
    if ((threadIdx.x & 63) == 0) atomicAdd(loss_acc, lrow);
}

// ---- kernel 3: finalize loss ----
__global__ void fin_kernel(const float* __restrict__ loss_acc,
                           float* __restrict__ out) {
    if (threadIdx.x == 0) {
        float mean_sq = (*loss_acc) / (float)((size_t)N_ROWS * DIM);
        out[0] = 1.25f * mean_sq;  // q_loss + COMMITMENT_COST * e_loss
    }
}

extern "C" void kernel_launch(void* const* d_in, const int* in_sizes, int n_in,
                              void* d_out, int out_size, void* d_ws, size_t ws_size,
                              hipStream_t stream) {
    const float* x  = (const float*)d_in[0];
    const float* cb = (const float*)d_in[1];
    float* out = (float*)d_out;

    float* loss_acc = (float*)d_ws;                 // 4 B accumulator
    float* esq      = (float*)((char*)d_ws + 256);  // 512 floats

    hipMemsetAsync(d_ws, 0, 4, stream);             // zero loss accumulator
    esq_kernel<<<2, 256, 0, stream>>>(cb, esq);
    vq_kernel<<<N_ROWS / 256, 256, 0, stream>>>(x, cb, esq, out, loss_acc);
    fin_kernel<<<1, 64, 0, stream>>>(loss_acc, out);
}